// Round 10
// baseline (470.853 us; speedup 1.0000x reference)
//
#include <hip/hip_runtime.h>

// ChebTimeConv: N=50000, E=1.6M, H=4, F_IN=F_OUT=32, K=4, Q=1.
// CSR build: binned counting sort (bin -> bucket_count -> scan -> scatter).
// SpMM: feature-chunked passes ([chunk][node][32f] bf16 mirrors, 3.2 MB
// per-pass working set < 4 MiB/XCD L2), 8 lanes/edge x uint2, unroll 8.
// This round: degree-sorted node permutation (counting sort over cnt) so
// the 8 node-groups of a wave have ~equal degree -> kill max-deg padding.
// CSR entry: (col<<16)|bf16(lap). edge_index arrives int32.

#define FEAT 128   // H * F_IN
#define GOUT 32    // F_OUT
#define NCH 4      // feature chunks
#define CHF 32     // feats per chunk
#define SCB 256
#define CH 4096    // edges per bin block
#define WCAP 16384 // scatter LDS window entries
#define CAP 12032  // staging slots per bucket
#define TROW 160   // padded LDS row for cvt kernel
#define UNR 8      // spmm gather unroll

typedef unsigned int uint;
typedef unsigned short ushort;

__device__ __forceinline__ ushort f2bf(float f) {
    uint u = __float_as_uint(f);
    return (ushort)((u + 0x7fffu + ((u >> 16) & 1u)) >> 16);   // RNE
}
__device__ __forceinline__ float bflo(uint u) { return __uint_as_float(u << 16); }
__device__ __forceinline__ float bfhi(uint u) { return __uint_as_float(u & 0xffff0000u); }
__device__ __forceinline__ int tidx(int i) { return i + ((i >> 4) << 2); }

// ---- phase 1: bin edges into per-(block,bucket) staging runs ----
__global__ __launch_bounds__(1024) void bin_kernel(
    const int* __restrict__ ei, const float* __restrict__ ew, int E,
    int* __restrict__ bucketCursor, uint2* __restrict__ staging) {
    __shared__ int hist[256];
    __shared__ int base[256];
    int e0 = blockIdx.x * CH;
    int e1 = min(e0 + CH, E);
    int t = threadIdx.x;
    if (t < 256) hist[t] = 0;
    __syncthreads();
    for (int e = e0 + t; e < e1; e += 1024) {
        int r = ei[e], c = ei[(size_t)E + e];
        if (r != c) atomicAdd(&hist[r >> 8], 1);
    }
    __syncthreads();
    if (t < 256) {
        int h = hist[t];
        if (h > 0) {
            int run = atomicAdd(&bucketCursor[t], h);
            base[t] = t * CAP + run;
        }
        hist[t] = 0;
    }
    __syncthreads();
    for (int e = e0 + t; e < e1; e += 1024) {
        int r = ei[e], c = ei[(size_t)E + e];
        if (r == c) continue;
        float w = ew[e];
        int bk = r >> 8;
        int j = atomicAdd(&hist[bk], 1);
        int idx = base[bk] + j;
        if (idx < (bk + 1) * CAP)   // impossible-overflow guard
            staging[idx] = make_uint2(__float_as_uint(w), ((uint)c << 16) | (uint)(r & 255));
    }
}

// ---- per-row counts from staging (contiguous reads, LDS hist) ----
__global__ __launch_bounds__(256) void bucket_count_kernel(
    const uint2* __restrict__ staging, const int* __restrict__ bucketCursor,
    int* __restrict__ cnt, int n) {
    __shared__ int hist[256];
    int b = blockIdx.x;
    int t = threadIdx.x;
    hist[t] = 0;
    __syncthreads();
    int nrec = bucketCursor[b];
    const uint2* src = staging + (size_t)b * CAP;
    for (int k = t; k < nrec; k += 256)
        atomicAdd(&hist[src[k].y & 255], 1);
    __syncthreads();
    int r = (b << 8) + t;
    if (r < n) cnt[r] = hist[t];
}

// ---- two-level scan (dinv folded into scan1) ----
__global__ void scan1_kernel(const int* __restrict__ cnt, int* __restrict__ partial,
                             int* __restrict__ blockSums, float* __restrict__ dinv, int n) {
    __shared__ int buf[2][SCB];
    int t = threadIdx.x;
    int i = blockIdx.x * SCB + t;
    int v = (i < n) ? cnt[i] : 0;
    if (i < n) dinv[i] = (v > 0) ? rsqrtf((float)v) : 0.0f;
    buf[0][t] = v;
    __syncthreads();
    int src = 0;
    for (int off = 1; off < SCB; off <<= 1) {
        int d = src ^ 1;
        buf[d][t] = buf[src][t] + ((t >= off) ? buf[src][t - off] : 0);
        __syncthreads();
        src = d;
    }
    int incl = buf[src][t];
    if (i < n) partial[i] = incl - v;
    if (t == SCB - 1) blockSums[blockIdx.x] = incl;
}

__global__ void scan2_kernel(const int* __restrict__ blockSums, int* __restrict__ blockOffsets,
                             int nb, int* __restrict__ total_out) {
    __shared__ int buf[2][SCB];
    __shared__ int carry_s;
    if (threadIdx.x == 0) carry_s = 0;
    __syncthreads();
    for (int base = 0; base < nb; base += SCB) {
        int i = base + (int)threadIdx.x;
        int v = (i < nb) ? blockSums[i] : 0;
        buf[0][threadIdx.x] = v;
        __syncthreads();
        int src = 0;
        for (int off = 1; off < SCB; off <<= 1) {
            int d = src ^ 1;
            buf[d][threadIdx.x] = buf[src][threadIdx.x] +
                                  ((threadIdx.x >= (unsigned)off) ? buf[src][threadIdx.x - off] : 0);
            __syncthreads();
            src = d;
        }
        int incl = buf[src][threadIdx.x];
        int c = carry_s;
        if (i < nb) blockOffsets[i] = c + incl - v;
        __syncthreads();
        if (threadIdx.x == SCB - 1) carry_s = c + incl;
        __syncthreads();
    }
    if (threadIdx.x == 0) *total_out = carry_s;
}

__global__ void scan3_kernel(const int* __restrict__ partial, const int* __restrict__ blockOffsets,
                             int* __restrict__ offsets, int n) {
    int i = blockIdx.x * blockDim.x + threadIdx.x;
    if (i < n) offsets[i] = partial[i] + blockOffsets[i / SCB];
}

// ---- degree counting sort: hist -> scan -> scatter => perm ----
__global__ __launch_bounds__(256) void deg_hist_kernel(
    const int* __restrict__ cnt, int* __restrict__ dhist, int n) {
    __shared__ int h[256];
    int t = threadIdx.x;
    h[t] = 0;
    __syncthreads();
    int i = blockIdx.x * 256 + t;
    if (i < n) atomicAdd(&h[min(cnt[i], 255)], 1);
    __syncthreads();
    if (h[t] > 0) atomicAdd(&dhist[t], h[t]);
}

__global__ __launch_bounds__(256) void deg_scan_kernel(
    const int* __restrict__ dhist, int* __restrict__ dbase) {
    __shared__ int buf[2][256];
    int t = threadIdx.x;
    int v = dhist[t];
    buf[0][t] = v;
    __syncthreads();
    int src = 0;
    for (int off = 1; off < 256; off <<= 1) {
        int d = src ^ 1;
        buf[d][t] = buf[src][t] + ((t >= off) ? buf[src][t - off] : 0);
        __syncthreads();
        src = d;
    }
    dbase[t] = buf[src][t] - v;   // exclusive
}

__global__ __launch_bounds__(256) void deg_scatter_kernel(
    const int* __restrict__ cnt, const int* __restrict__ dbase,
    int* __restrict__ dcur, int* __restrict__ perm, int n) {
    int i = blockIdx.x * 256 + threadIdx.x;
    if (i >= n) return;
    int d = min(cnt[i], 255);
    int pos = dbase[d] + atomicAdd(&dcur[d], 1);
    perm[pos] = i;
}

// ---- phase 2: per-bucket scatter via LDS window -> coalesced csr write ----
__global__ __launch_bounds__(256) void scatter_kernel(
    const uint2* __restrict__ staging, const int* __restrict__ bucketCursor,
    const int* __restrict__ offsets, const float* __restrict__ dinv,
    uint* __restrict__ csr, int n) {
    __shared__ uint win[WCAP];          // 64 KB
    __shared__ int roff[256];
    __shared__ int rcur[256];
    __shared__ float dloc[256];
    int b = blockIdx.x;
    int r0 = b << 8;
    int nrows = min(256, n - r0);
    int t = threadIdx.x;
    if (t < nrows) {
        roff[t] = offsets[r0 + t];
        dloc[t] = dinv[r0 + t];
    }
    rcur[t] = 0;
    __syncthreads();
    int wbeg = roff[0];
    int nrec = bucketCursor[b];
    bool fit = (nrec <= WCAP);
    const uint2* src = staging + (size_t)b * CAP;
    for (int k = t; k < nrec; k += 256) {
        uint2 rec = src[k];
        int col = rec.y >> 16;
        int rl = rec.y & 255;
        float lap = -dloc[rl] * __uint_as_float(rec.x) * dinv[col];
        uint colap = ((uint)col << 16) | (uint)f2bf(lap);
        int pos = roff[rl] + atomicAdd(&rcur[rl], 1);
        if (fit) win[pos - wbeg] = colap;
        else csr[pos] = colap;
    }
    __syncthreads();
    if (fit)
        for (int k = t; k < nrec; k += 256) csr[wbeg + k] = win[k];
}

// ---- fused: x -> CHUNKED bf16 mirror, plus out = bias + x*W0 ----
__global__ __launch_bounds__(256) void cvt_einsum0_kernel(
    const float* __restrict__ x, ushort* __restrict__ xb,
    const float* __restrict__ W0, const float* __restrict__ bias,
    float* __restrict__ out, int n) {
    __shared__ __align__(16) float4 sW4[FEAT * GOUT / 4];
    __shared__ __align__(16) float sT[8 * TROW];
    const float* sW = (const float*)sW4;
    int t = threadIdx.x;
    const float4* wsrc = (const float4*)W0;
    for (int idx = t; idx < FEAT * GOUT / 4; idx += 256) sW4[idx] = wsrc[idx];
    int node = blockIdx.x * 8 + (t >> 5);
    int f0 = 4 * (t & 31);
    float4 v = make_float4(0.f, 0.f, 0.f, 0.f);
    if (node < n) {
        v = *(const float4*)(x + (size_t)node * FEAT + f0);
        ushort4 o;
        o.x = f2bf(v.x); o.y = f2bf(v.y); o.z = f2bf(v.z); o.w = f2bf(v.w);
        int j0 = f0 >> 5;                 // chunk of these 4 feats
        *(ushort4*)(xb + ((size_t)j0 * n + node) * CHF + (f0 & 31)) = o;
    }
    int nl = t >> 5;
    *(float4*)&sT[nl * TROW + tidx(f0)] = v;
    __syncthreads();
    int l32 = t & 31;
    int q = l32 & 7;
    int part = l32 >> 3;
    float4 a4 = make_float4(0.f, 0.f, 0.f, 0.f);
#pragma unroll
    for (int j = 0; j < 8; ++j) {
        float4 t4 = *(const float4*)&sT[nl * TROW + tidx(part * 32 + 4 * j)];
        const float* wv0 = &sW[(part * 32 + 4 * j) * GOUT + 4 * q];
        float4 w0 = *(const float4*)(wv0);
        float4 w1 = *(const float4*)(wv0 + GOUT);
        float4 w2 = *(const float4*)(wv0 + 2 * GOUT);
        float4 w3 = *(const float4*)(wv0 + 3 * GOUT);
        a4.x += t4.x * w0.x + t4.y * w1.x + t4.z * w2.x + t4.w * w3.x;
        a4.y += t4.x * w0.y + t4.y * w1.y + t4.z * w2.y + t4.w * w3.y;
        a4.z += t4.x * w0.z + t4.y * w1.z + t4.z * w2.z + t4.w * w3.z;
        a4.w += t4.x * w0.w + t4.y * w1.w + t4.z * w2.w + t4.w * w3.w;
    }
    a4.x += __shfl_down(a4.x, 8);  a4.y += __shfl_down(a4.y, 8);
    a4.z += __shfl_down(a4.z, 8);  a4.w += __shfl_down(a4.w, 8);
    a4.x += __shfl_down(a4.x, 16); a4.y += __shfl_down(a4.y, 16);
    a4.z += __shfl_down(a4.z, 16); a4.w += __shfl_down(a4.w, 16);
    if (part == 0 && node < n) {
        const float4 b4 = *(const float4*)(bias + 4 * q);
        float4 r;
        r.x = a4.x + b4.x; r.y = a4.y + b4.y; r.z = a4.z + b4.z; r.w = a4.w + b4.w;
        *(float4*)(out + (size_t)node * GOUT + 4 * q) = r;
    }
}

// ---- chunked SpMM pass + partial einsum, degree-sorted node order ----
// grid = NCH * nbj (j-major). Wave = 8 nodes x 8 lanes; lane = uint2 (4 feats).
__global__ __launch_bounds__(512) void spmm_chunk_kernel(
    const ushort* __restrict__ inb, const ushort* __restrict__ sub,
    ushort* __restrict__ outb, const int* __restrict__ offsets,
    const uint* __restrict__ csr, const int* __restrict__ perm,
    const float* __restrict__ Wk,
    float* __restrict__ out, int n, int has_sub, int nbj) {
    __shared__ __align__(16) float sW[CHF * GOUT];   // 4 KB: W rows of this chunk
    __shared__ float sT2[8][8][CHF + 1];             // 8.25 KB, +1 pad (banks)
    int j = blockIdx.x / nbj;
    int b = blockIdx.x % nbj;
    int t = threadIdx.x;
    const float4* wsrc = (const float4*)(Wk + j * CHF * GOUT);
    for (int i2 = t; i2 < CHF * GOUT / 4; i2 += 512) ((float4*)sW)[i2] = wsrc[i2];
    int w = t >> 6, lane = t & 63, s = lane >> 3, u = lane & 7;
    int idx0 = b * 64 + w * 8 + s;
    int node = (idx0 < n) ? perm[idx0] : n;          // sentinel n: all guards off
    int beg = 0, deg = 0;
    if (node < n) { beg = offsets[node]; deg = offsets[node + 1] - beg; }
    int m = deg;
    m = max(m, __shfl_xor(m, 8));
    m = max(m, __shfl_xor(m, 16));
    m = max(m, __shfl_xor(m, 32));
    const uint2* inb_u2 = (const uint2*)inb;
    size_t jb2 = (size_t)j * n * 8;                  // chunk base, uint2 units
    size_t obase = jb2 + (size_t)node * 8 + u;
    uint2 sv = make_uint2(0u, 0u);
    if (has_sub && node < n) sv = ((const uint2*)sub)[obase];   // early, independent
    float a0 = 0.f, a1 = 0.f, a2 = 0.f, a3 = 0.f;
    for (int it = 0; it < m; it += UNR) {
        uint q[UNR];
        uint2 uu[UNR];
#pragma unroll
        for (int k = 0; k < UNR; ++k) {
            int idx = it + k;
            q[k] = (idx < deg) ? csr[beg + idx] : 0u;
        }
#pragma unroll
        for (int k = 0; k < UNR; ++k)
            uu[k] = inb_u2[jb2 + (size_t)(q[k] >> 16) * 8 + u];
#pragma unroll
        for (int k = 0; k < UNR; ++k) {
            float l = bflo(q[k]);
            a0 += l * bflo(uu[k].x);
            a1 += l * bfhi(uu[k].x);
            a2 += l * bflo(uu[k].y);
            a3 += l * bfhi(uu[k].y);
        }
    }
    if (has_sub) {
        a0 = 2.f * a0 - bflo(sv.x);
        a1 = 2.f * a1 - bfhi(sv.x);
        a2 = 2.f * a2 - bflo(sv.y);
        a3 = 2.f * a3 - bfhi(sv.y);
    }
    if (node < n) {
        uint2 o;
        o.x = (uint)f2bf(a0) | ((uint)f2bf(a1) << 16);
        o.y = (uint)f2bf(a2) | ((uint)f2bf(a3) << 16);
        ((uint2*)outb)[obase] = o;
    }
    sT2[w][s][4 * u + 0] = a0;
    sT2[w][s][4 * u + 1] = a1;
    sT2[w][s][4 * u + 2] = a2;
    sT2[w][s][4 * u + 3] = a3;
    __syncthreads();                      // covers sW staging; sT2 is wave-local
    // partial einsum: lane (s,u) -> out[node_s, u + 8k], k=0..3
    float e0 = 0.f, e1 = 0.f, e2 = 0.f, e3 = 0.f;
#pragma unroll
    for (int i = 0; i < CHF; ++i) {
        float tv = sT2[w][s][i];          // broadcast across u
        e0 += tv * sW[i * GOUT + u];
        e1 += tv * sW[i * GOUT + u + 8];
        e2 += tv * sW[i * GOUT + u + 16];
        e3 += tv * sW[i * GOUT + u + 24];
    }
    if (node < n) {
        float* po = out + (size_t)node * GOUT;
        atomicAdd(po + u, e0);
        atomicAdd(po + u + 8, e1);
        atomicAdd(po + u + 16, e2);
        atomicAdd(po + u + 24, e3);
    }
}

extern "C" void kernel_launch(void* const* d_in, const int* in_sizes, int n_in,
                              void* d_out, int out_size, void* d_ws, size_t ws_size,
                              hipStream_t stream) {
    const float* x = (const float*)d_in[0];
    const int* ei = (const int*)d_in[1];     // int32 per harness contract
    const float* ew = (const float*)d_in[2];
    const float* W = (const float*)d_in[3];
    const float* bias = (const float*)d_in[4];
    float* out = (float*)d_out;

    const int N = in_sizes[0] / FEAT;   // 50000
    const int E = in_sizes[1] / 2;      // 1600000
    const int NB = (N + SCB - 1) / SCB;
    const int NBUK = (N + 255) >> 8;    // 196
    // spmm node-blocks (64 nodes/block), padded to x8 for stable XCD mapping
    const int NBJ = (((N + 63) / 64 + 7) / 8) * 8;   // 784

    char* p = (char*)d_ws;
    auto alloc = [&](size_t bytes) {
        char* q = p;
        p += (bytes + 255) & ~(size_t)255;
        return q;
    };
    int* cnt = (int*)alloc((size_t)N * 4);
    int* offsets = (int*)alloc(((size_t)N + 1) * 4);
    float* dinv = (float*)alloc((size_t)N * 4);
    int* partial = (int*)alloc((size_t)N * 4);
    int* blockSums = (int*)alloc((size_t)NB * 4);
    int* blockOffsets = (int*)alloc((size_t)NB * 4);
    int* bucketCursor = (int*)alloc((size_t)NBUK * 4);
    int* dhist = (int*)alloc(512 * 4);           // dhist[256] + dcur[256], one memset
    int* dcur = dhist + 256;
    int* dbase = (int*)alloc(256 * 4);
    int* perm = (int*)alloc((size_t)N * 4);
    uint* csr = (uint*)alloc(((size_t)E + 64) * 4);  // +pad: predicated over-reads
    ushort* xb = (ushort*)alloc((size_t)N * FEAT * 2);
    ushort* Ab = (ushort*)alloc((size_t)N * FEAT * 2);
    ushort* Bb = (ushort*)alloc((size_t)N * FEAT * 2);
    uint2* staging = (uint2*)Ab;   // aliases Ab+Bb (dead before first spmm)
    (void)ws_size;

    hipMemsetAsync(bucketCursor, 0, (size_t)NBUK * 4, stream);
    hipMemsetAsync(dhist, 0, 512 * 4, stream);

    bin_kernel<<<(E + CH - 1) / CH, 1024, 0, stream>>>(ei, ew, E, bucketCursor, staging);
    bucket_count_kernel<<<NBUK, 256, 0, stream>>>(staging, bucketCursor, cnt, N);
    scan1_kernel<<<NB, SCB, 0, stream>>>(cnt, partial, blockSums, dinv, N);
    scan2_kernel<<<1, SCB, 0, stream>>>(blockSums, blockOffsets, NB, offsets + N);
    scan3_kernel<<<NB, SCB, 0, stream>>>(partial, blockOffsets, offsets, N);
    deg_hist_kernel<<<NBUK, 256, 0, stream>>>(cnt, dhist, N);
    deg_scan_kernel<<<1, 256, 0, stream>>>(dhist, dbase);
    deg_scatter_kernel<<<NBUK, 256, 0, stream>>>(cnt, dbase, dcur, perm, N);
    scatter_kernel<<<NBUK, 256, 0, stream>>>(staging, bucketCursor, offsets, dinv, csr, N);

    // out = bias + x*W0 ; xb = chunked bf16(x)
    cvt_einsum0_kernel<<<(N + 7) / 8, 256, 0, stream>>>(x, xb, W, bias, out, N);

    dim3 sg(NCH * NBJ);
    // Tx1 = S(x);            out += Tx1*W1
    spmm_chunk_kernel<<<sg, 512, 0, stream>>>(xb, nullptr, Ab, offsets, csr, perm,
                                              W + 1 * FEAT * GOUT, out, N, 0, NBJ);
    // Tx2 = 2*S(Tx1) - x;    out += Tx2*W2
    spmm_chunk_kernel<<<sg, 512, 0, stream>>>(Ab, xb, Bb, offsets, csr, perm,
                                              W + 2 * FEAT * GOUT, out, N, 1, NBJ);
    // Tx3 = 2*S(Tx2) - Tx1;  out += Tx3*W3   (outb aliases sub; read-before-write)
    spmm_chunk_kernel<<<sg, 512, 0, stream>>>(Bb, Ab, Ab, offsets, csr, perm,
                                              W + 3 * FEAT * GOUT, out, N, 1, NBJ);
}

// Round 11
// 383.665 us; speedup vs baseline: 1.2273x; 1.2273x over previous
//
#include <hip/hip_runtime.h>

// ChebTimeConv: N=50000, E=1.6M, H=4, F_IN=F_OUT=32, K=4, Q=1.
// CSR build: binned counting sort (bin -> bucket_count -> scan -> scatter).
// SpMM: feature-chunked passes ([chunk][node][32f] bf16 mirrors, 3.2 MB
// per-pass working set < 4 MiB/XCD L2), 8 lanes/edge x uint2, unroll 8,
// degree-sorted node permutation (wave's 8 node-groups ~equal degree).
// This round: deg_scatter uses per-block LDS aggregation -> ~50 global
// atomics/block instead of 256 (was 90 us of global-atomic serialization).
// CSR entry: (col<<16)|bf16(lap). edge_index arrives int32.

#define FEAT 128   // H * F_IN
#define GOUT 32    // F_OUT
#define NCH 4      // feature chunks
#define CHF 32     // feats per chunk
#define SCB 256
#define CH 4096    // edges per bin block
#define WCAP 16384 // scatter LDS window entries
#define CAP 12032  // staging slots per bucket
#define TROW 160   // padded LDS row for cvt kernel
#define UNR 8      // spmm gather unroll

typedef unsigned int uint;
typedef unsigned short ushort;

__device__ __forceinline__ ushort f2bf(float f) {
    uint u = __float_as_uint(f);
    return (ushort)((u + 0x7fffu + ((u >> 16) & 1u)) >> 16);   // RNE
}
__device__ __forceinline__ float bflo(uint u) { return __uint_as_float(u << 16); }
__device__ __forceinline__ float bfhi(uint u) { return __uint_as_float(u & 0xffff0000u); }
__device__ __forceinline__ int tidx(int i) { return i + ((i >> 4) << 2); }

// ---- phase 1: bin edges into per-(block,bucket) staging runs ----
__global__ __launch_bounds__(1024) void bin_kernel(
    const int* __restrict__ ei, const float* __restrict__ ew, int E,
    int* __restrict__ bucketCursor, uint2* __restrict__ staging) {
    __shared__ int hist[256];
    __shared__ int base[256];
    int e0 = blockIdx.x * CH;
    int e1 = min(e0 + CH, E);
    int t = threadIdx.x;
    if (t < 256) hist[t] = 0;
    __syncthreads();
    for (int e = e0 + t; e < e1; e += 1024) {
        int r = ei[e], c = ei[(size_t)E + e];
        if (r != c) atomicAdd(&hist[r >> 8], 1);
    }
    __syncthreads();
    if (t < 256) {
        int h = hist[t];
        if (h > 0) {
            int run = atomicAdd(&bucketCursor[t], h);
            base[t] = t * CAP + run;
        }
        hist[t] = 0;
    }
    __syncthreads();
    for (int e = e0 + t; e < e1; e += 1024) {
        int r = ei[e], c = ei[(size_t)E + e];
        if (r == c) continue;
        float w = ew[e];
        int bk = r >> 8;
        int j = atomicAdd(&hist[bk], 1);
        int idx = base[bk] + j;
        if (idx < (bk + 1) * CAP)   // impossible-overflow guard
            staging[idx] = make_uint2(__float_as_uint(w), ((uint)c << 16) | (uint)(r & 255));
    }
}

// ---- per-row counts from staging (contiguous reads, LDS hist) ----
__global__ __launch_bounds__(256) void bucket_count_kernel(
    const uint2* __restrict__ staging, const int* __restrict__ bucketCursor,
    int* __restrict__ cnt, int n) {
    __shared__ int hist[256];
    int b = blockIdx.x;
    int t = threadIdx.x;
    hist[t] = 0;
    __syncthreads();
    int nrec = bucketCursor[b];
    const uint2* src = staging + (size_t)b * CAP;
    for (int k = t; k < nrec; k += 256)
        atomicAdd(&hist[src[k].y & 255], 1);
    __syncthreads();
    int r = (b << 8) + t;
    if (r < n) cnt[r] = hist[t];
}

// ---- two-level scan (dinv folded into scan1) ----
__global__ void scan1_kernel(const int* __restrict__ cnt, int* __restrict__ partial,
                             int* __restrict__ blockSums, float* __restrict__ dinv, int n) {
    __shared__ int buf[2][SCB];
    int t = threadIdx.x;
    int i = blockIdx.x * SCB + t;
    int v = (i < n) ? cnt[i] : 0;
    if (i < n) dinv[i] = (v > 0) ? rsqrtf((float)v) : 0.0f;
    buf[0][t] = v;
    __syncthreads();
    int src = 0;
    for (int off = 1; off < SCB; off <<= 1) {
        int d = src ^ 1;
        buf[d][t] = buf[src][t] + ((t >= off) ? buf[src][t - off] : 0);
        __syncthreads();
        src = d;
    }
    int incl = buf[src][t];
    if (i < n) partial[i] = incl - v;
    if (t == SCB - 1) blockSums[blockIdx.x] = incl;
}

__global__ void scan2_kernel(const int* __restrict__ blockSums, int* __restrict__ blockOffsets,
                             int nb, int* __restrict__ total_out) {
    __shared__ int buf[2][SCB];
    __shared__ int carry_s;
    if (threadIdx.x == 0) carry_s = 0;
    __syncthreads();
    for (int base = 0; base < nb; base += SCB) {
        int i = base + (int)threadIdx.x;
        int v = (i < nb) ? blockSums[i] : 0;
        buf[0][threadIdx.x] = v;
        __syncthreads();
        int src = 0;
        for (int off = 1; off < SCB; off <<= 1) {
            int d = src ^ 1;
            buf[d][threadIdx.x] = buf[src][threadIdx.x] +
                                  ((threadIdx.x >= (unsigned)off) ? buf[src][threadIdx.x - off] : 0);
            __syncthreads();
            src = d;
        }
        int incl = buf[src][threadIdx.x];
        int c = carry_s;
        if (i < nb) blockOffsets[i] = c + incl - v;
        __syncthreads();
        if (threadIdx.x == SCB - 1) carry_s = c + incl;
        __syncthreads();
    }
    if (threadIdx.x == 0) *total_out = carry_s;
}

__global__ void scan3_kernel(const int* __restrict__ partial, const int* __restrict__ blockOffsets,
                             int* __restrict__ offsets, int n) {
    int i = blockIdx.x * blockDim.x + threadIdx.x;
    if (i < n) offsets[i] = partial[i] + blockOffsets[i / SCB];
}

// ---- degree counting sort: hist -> scan -> scatter => perm ----
__global__ __launch_bounds__(256) void deg_hist_kernel(
    const int* __restrict__ cnt, int* __restrict__ dhist, int n) {
    __shared__ int h[256];
    int t = threadIdx.x;
    h[t] = 0;
    __syncthreads();
    int i = blockIdx.x * 256 + t;
    if (i < n) atomicAdd(&h[min(cnt[i], 255)], 1);
    __syncthreads();
    if (h[t] > 0) atomicAdd(&dhist[t], h[t]);
}

__global__ __launch_bounds__(256) void deg_scan_kernel(
    const int* __restrict__ dhist, int* __restrict__ dbase) {
    __shared__ int buf[2][256];
    int t = threadIdx.x;
    int v = dhist[t];
    buf[0][t] = v;
    __syncthreads();
    int src = 0;
    for (int off = 1; off < 256; off <<= 1) {
        int d = src ^ 1;
        buf[d][t] = buf[src][t] + ((t >= off) ? buf[src][t - off] : 0);
        __syncthreads();
        src = d;
    }
    dbase[t] = buf[src][t] - v;   // exclusive
}

// per-block LDS aggregation: one global atomic per distinct degree per block
__global__ __launch_bounds__(256) void deg_scatter_kernel(
    const int* __restrict__ cnt, const int* __restrict__ dbase,
    int* __restrict__ dcur, int* __restrict__ perm, int n) {
    __shared__ int h[256];      // block hist
    __shared__ int run[256];    // this block's reserved run base per degree
    __shared__ int lc[256];     // local cursor
    int t = threadIdx.x;
    int i = blockIdx.x * 256 + t;
    int d = (i < n) ? min(cnt[i], 255) : -1;
    h[t] = 0;
    lc[t] = 0;
    __syncthreads();
    if (d >= 0) atomicAdd(&h[d], 1);
    __syncthreads();
    if (h[t] > 0) run[t] = atomicAdd(&dcur[t], h[t]);
    __syncthreads();
    if (d >= 0) {
        int r = atomicAdd(&lc[d], 1);
        perm[dbase[d] + run[d] + r] = i;
    }
}

// ---- phase 2: per-bucket scatter via LDS window -> coalesced csr write ----
__global__ __launch_bounds__(256) void scatter_kernel(
    const uint2* __restrict__ staging, const int* __restrict__ bucketCursor,
    const int* __restrict__ offsets, const float* __restrict__ dinv,
    uint* __restrict__ csr, int n) {
    __shared__ uint win[WCAP];          // 64 KB
    __shared__ int roff[256];
    __shared__ int rcur[256];
    __shared__ float dloc[256];
    int b = blockIdx.x;
    int r0 = b << 8;
    int nrows = min(256, n - r0);
    int t = threadIdx.x;
    if (t < nrows) {
        roff[t] = offsets[r0 + t];
        dloc[t] = dinv[r0 + t];
    }
    rcur[t] = 0;
    __syncthreads();
    int wbeg = roff[0];
    int nrec = bucketCursor[b];
    bool fit = (nrec <= WCAP);
    const uint2* src = staging + (size_t)b * CAP;
    for (int k = t; k < nrec; k += 256) {
        uint2 rec = src[k];
        int col = rec.y >> 16;
        int rl = rec.y & 255;
        float lap = -dloc[rl] * __uint_as_float(rec.x) * dinv[col];
        uint colap = ((uint)col << 16) | (uint)f2bf(lap);
        int pos = roff[rl] + atomicAdd(&rcur[rl], 1);
        if (fit) win[pos - wbeg] = colap;
        else csr[pos] = colap;
    }
    __syncthreads();
    if (fit)
        for (int k = t; k < nrec; k += 256) csr[wbeg + k] = win[k];
}

// ---- fused: x -> CHUNKED bf16 mirror, plus out = bias + x*W0 ----
__global__ __launch_bounds__(256) void cvt_einsum0_kernel(
    const float* __restrict__ x, ushort* __restrict__ xb,
    const float* __restrict__ W0, const float* __restrict__ bias,
    float* __restrict__ out, int n) {
    __shared__ __align__(16) float4 sW4[FEAT * GOUT / 4];
    __shared__ __align__(16) float sT[8 * TROW];
    const float* sW = (const float*)sW4;
    int t = threadIdx.x;
    const float4* wsrc = (const float4*)W0;
    for (int idx = t; idx < FEAT * GOUT / 4; idx += 256) sW4[idx] = wsrc[idx];
    int node = blockIdx.x * 8 + (t >> 5);
    int f0 = 4 * (t & 31);
    float4 v = make_float4(0.f, 0.f, 0.f, 0.f);
    if (node < n) {
        v = *(const float4*)(x + (size_t)node * FEAT + f0);
        ushort4 o;
        o.x = f2bf(v.x); o.y = f2bf(v.y); o.z = f2bf(v.z); o.w = f2bf(v.w);
        int j0 = f0 >> 5;                 // chunk of these 4 feats
        *(ushort4*)(xb + ((size_t)j0 * n + node) * CHF + (f0 & 31)) = o;
    }
    int nl = t >> 5;
    *(float4*)&sT[nl * TROW + tidx(f0)] = v;
    __syncthreads();
    int l32 = t & 31;
    int q = l32 & 7;
    int part = l32 >> 3;
    float4 a4 = make_float4(0.f, 0.f, 0.f, 0.f);
#pragma unroll
    for (int j = 0; j < 8; ++j) {
        float4 t4 = *(const float4*)&sT[nl * TROW + tidx(part * 32 + 4 * j)];
        const float* wv0 = &sW[(part * 32 + 4 * j) * GOUT + 4 * q];
        float4 w0 = *(const float4*)(wv0);
        float4 w1 = *(const float4*)(wv0 + GOUT);
        float4 w2 = *(const float4*)(wv0 + 2 * GOUT);
        float4 w3 = *(const float4*)(wv0 + 3 * GOUT);
        a4.x += t4.x * w0.x + t4.y * w1.x + t4.z * w2.x + t4.w * w3.x;
        a4.y += t4.x * w0.y + t4.y * w1.y + t4.z * w2.y + t4.w * w3.y;
        a4.z += t4.x * w0.z + t4.y * w1.z + t4.z * w2.z + t4.w * w3.z;
        a4.w += t4.x * w0.w + t4.y * w1.w + t4.z * w2.w + t4.w * w3.w;
    }
    a4.x += __shfl_down(a4.x, 8);  a4.y += __shfl_down(a4.y, 8);
    a4.z += __shfl_down(a4.z, 8);  a4.w += __shfl_down(a4.w, 8);
    a4.x += __shfl_down(a4.x, 16); a4.y += __shfl_down(a4.y, 16);
    a4.z += __shfl_down(a4.z, 16); a4.w += __shfl_down(a4.w, 16);
    if (part == 0 && node < n) {
        const float4 b4 = *(const float4*)(bias + 4 * q);
        float4 r;
        r.x = a4.x + b4.x; r.y = a4.y + b4.y; r.z = a4.z + b4.z; r.w = a4.w + b4.w;
        *(float4*)(out + (size_t)node * GOUT + 4 * q) = r;
    }
}

// ---- chunked SpMM pass + partial einsum, degree-sorted node order ----
// grid = NCH * nbj (j-major). Wave = 8 nodes x 8 lanes; lane = uint2 (4 feats).
__global__ __launch_bounds__(512) void spmm_chunk_kernel(
    const ushort* __restrict__ inb, const ushort* __restrict__ sub,
    ushort* __restrict__ outb, const int* __restrict__ offsets,
    const uint* __restrict__ csr, const int* __restrict__ perm,
    const float* __restrict__ Wk,
    float* __restrict__ out, int n, int has_sub, int nbj) {
    __shared__ __align__(16) float sW[CHF * GOUT];   // 4 KB: W rows of this chunk
    __shared__ float sT2[8][8][CHF + 1];             // 8.25 KB, +1 pad (banks)
    int j = blockIdx.x / nbj;
    int b = blockIdx.x % nbj;
    int t = threadIdx.x;
    const float4* wsrc = (const float4*)(Wk + j * CHF * GOUT);
    for (int i2 = t; i2 < CHF * GOUT / 4; i2 += 512) ((float4*)sW)[i2] = wsrc[i2];
    int w = t >> 6, lane = t & 63, s = lane >> 3, u = lane & 7;
    int idx0 = b * 64 + w * 8 + s;
    int node = (idx0 < n) ? perm[idx0] : n;          // sentinel n: all guards off
    int beg = 0, deg = 0;
    if (node < n) { beg = offsets[node]; deg = offsets[node + 1] - beg; }
    int m = deg;
    m = max(m, __shfl_xor(m, 8));
    m = max(m, __shfl_xor(m, 16));
    m = max(m, __shfl_xor(m, 32));
    const uint2* inb_u2 = (const uint2*)inb;
    size_t jb2 = (size_t)j * n * 8;                  // chunk base, uint2 units
    size_t obase = jb2 + (size_t)node * 8 + u;
    uint2 sv = make_uint2(0u, 0u);
    if (has_sub && node < n) sv = ((const uint2*)sub)[obase];   // early, independent
    float a0 = 0.f, a1 = 0.f, a2 = 0.f, a3 = 0.f;
    for (int it = 0; it < m; it += UNR) {
        uint q[UNR];
        uint2 uu[UNR];
#pragma unroll
        for (int k = 0; k < UNR; ++k) {
            int idx = it + k;
            q[k] = (idx < deg) ? csr[beg + idx] : 0u;
        }
#pragma unroll
        for (int k = 0; k < UNR; ++k)
            uu[k] = inb_u2[jb2 + (size_t)(q[k] >> 16) * 8 + u];
#pragma unroll
        for (int k = 0; k < UNR; ++k) {
            float l = bflo(q[k]);
            a0 += l * bflo(uu[k].x);
            a1 += l * bfhi(uu[k].x);
            a2 += l * bflo(uu[k].y);
            a3 += l * bfhi(uu[k].y);
        }
    }
    if (has_sub) {
        a0 = 2.f * a0 - bflo(sv.x);
        a1 = 2.f * a1 - bfhi(sv.x);
        a2 = 2.f * a2 - bflo(sv.y);
        a3 = 2.f * a3 - bfhi(sv.y);
    }
    if (node < n) {
        uint2 o;
        o.x = (uint)f2bf(a0) | ((uint)f2bf(a1) << 16);
        o.y = (uint)f2bf(a2) | ((uint)f2bf(a3) << 16);
        ((uint2*)outb)[obase] = o;
    }
    sT2[w][s][4 * u + 0] = a0;
    sT2[w][s][4 * u + 1] = a1;
    sT2[w][s][4 * u + 2] = a2;
    sT2[w][s][4 * u + 3] = a3;
    __syncthreads();                      // covers sW staging; sT2 is wave-local
    // partial einsum: lane (s,u) -> out[node_s, u + 8k], k=0..3
    float e0 = 0.f, e1 = 0.f, e2 = 0.f, e3 = 0.f;
#pragma unroll
    for (int i = 0; i < CHF; ++i) {
        float tv = sT2[w][s][i];          // broadcast across u
        e0 += tv * sW[i * GOUT + u];
        e1 += tv * sW[i * GOUT + u + 8];
        e2 += tv * sW[i * GOUT + u + 16];
        e3 += tv * sW[i * GOUT + u + 24];
    }
    if (node < n) {
        float* po = out + (size_t)node * GOUT;
        atomicAdd(po + u, e0);
        atomicAdd(po + u + 8, e1);
        atomicAdd(po + u + 16, e2);
        atomicAdd(po + u + 24, e3);
    }
}

extern "C" void kernel_launch(void* const* d_in, const int* in_sizes, int n_in,
                              void* d_out, int out_size, void* d_ws, size_t ws_size,
                              hipStream_t stream) {
    const float* x = (const float*)d_in[0];
    const int* ei = (const int*)d_in[1];     // int32 per harness contract
    const float* ew = (const float*)d_in[2];
    const float* W = (const float*)d_in[3];
    const float* bias = (const float*)d_in[4];
    float* out = (float*)d_out;

    const int N = in_sizes[0] / FEAT;   // 50000
    const int E = in_sizes[1] / 2;      // 1600000
    const int NB = (N + SCB - 1) / SCB;
    const int NBUK = (N + 255) >> 8;    // 196
    // spmm node-blocks (64 nodes/block), padded to x8 for stable XCD mapping
    const int NBJ = (((N + 63) / 64 + 7) / 8) * 8;   // 784

    char* p = (char*)d_ws;
    auto alloc = [&](size_t bytes) {
        char* q = p;
        p += (bytes + 255) & ~(size_t)255;
        return q;
    };
    int* cnt = (int*)alloc((size_t)N * 4);
    int* offsets = (int*)alloc(((size_t)N + 1) * 4);
    float* dinv = (float*)alloc((size_t)N * 4);
    int* partial = (int*)alloc((size_t)N * 4);
    int* blockSums = (int*)alloc((size_t)NB * 4);
    int* blockOffsets = (int*)alloc((size_t)NB * 4);
    int* bucketCursor = (int*)alloc((size_t)NBUK * 4);
    int* dhist = (int*)alloc(512 * 4);           // dhist[256] + dcur[256], one memset
    int* dcur = dhist + 256;
    int* dbase = (int*)alloc(256 * 4);
    int* perm = (int*)alloc((size_t)N * 4);
    uint* csr = (uint*)alloc(((size_t)E + 64) * 4);  // +pad: predicated over-reads
    ushort* xb = (ushort*)alloc((size_t)N * FEAT * 2);
    ushort* Ab = (ushort*)alloc((size_t)N * FEAT * 2);
    ushort* Bb = (ushort*)alloc((size_t)N * FEAT * 2);
    uint2* staging = (uint2*)Ab;   // aliases Ab+Bb (dead before first spmm)
    (void)ws_size;

    hipMemsetAsync(bucketCursor, 0, (size_t)NBUK * 4, stream);
    hipMemsetAsync(dhist, 0, 512 * 4, stream);

    bin_kernel<<<(E + CH - 1) / CH, 1024, 0, stream>>>(ei, ew, E, bucketCursor, staging);
    bucket_count_kernel<<<NBUK, 256, 0, stream>>>(staging, bucketCursor, cnt, N);
    scan1_kernel<<<NB, SCB, 0, stream>>>(cnt, partial, blockSums, dinv, N);
    scan2_kernel<<<1, SCB, 0, stream>>>(blockSums, blockOffsets, NB, offsets + N);
    scan3_kernel<<<NB, SCB, 0, stream>>>(partial, blockOffsets, offsets, N);
    deg_hist_kernel<<<NBUK, 256, 0, stream>>>(cnt, dhist, N);
    deg_scan_kernel<<<1, 256, 0, stream>>>(dhist, dbase);
    deg_scatter_kernel<<<NBUK, 256, 0, stream>>>(cnt, dbase, dcur, perm, N);
    scatter_kernel<<<NBUK, 256, 0, stream>>>(staging, bucketCursor, offsets, dinv, csr, N);

    // out = bias + x*W0 ; xb = chunked bf16(x)
    cvt_einsum0_kernel<<<(N + 7) / 8, 256, 0, stream>>>(x, xb, W, bias, out, N);

    dim3 sg(NCH * NBJ);
    // Tx1 = S(x);            out += Tx1*W1
    spmm_chunk_kernel<<<sg, 512, 0, stream>>>(xb, nullptr, Ab, offsets, csr, perm,
                                              W + 1 * FEAT * GOUT, out, N, 0, NBJ);
    // Tx2 = 2*S(Tx1) - x;    out += Tx2*W2
    spmm_chunk_kernel<<<sg, 512, 0, stream>>>(Ab, xb, Bb, offsets, csr, perm,
                                              W + 2 * FEAT * GOUT, out, N, 1, NBJ);
    // Tx3 = 2*S(Tx2) - Tx1;  out += Tx3*W3   (outb aliases sub; read-before-write)
    spmm_chunk_kernel<<<sg, 512, 0, stream>>>(Bb, Ab, Ab, offsets, csr, perm,
                                              W + 3 * FEAT * GOUT, out, N, 1, NBJ);
}

// Round 12
// 373.037 us; speedup vs baseline: 1.2622x; 1.0285x over previous
//
#include <hip/hip_runtime.h>

// ChebTimeConv: N=50000, E=1.6M, H=4, F_IN=F_OUT=32, K=4, Q=1.
// CSR build: binned counting sort (bin -> bucket_count -> scan -> scatter).
// SpMM: feature-chunked passes ([chunk][node][32f] bf16 mirrors, 3.2 MB
// per-pass working set < 4 MiB/XCD L2), 8 lanes/edge x uint2, unroll 8.
// This round: LOCAL degree ranking per 64-node block (waves get rank-octets,
// padding 1.26 -> ~1.06) -- keeps all address locality, unlike the global
// degree sort (R11: FETCH 91->155 MB, net loss, reverted). Last spmm skips
// the dead outb store. CSR entry: (col<<16)|bf16(lap). edge_index int32.

#define FEAT 128   // H * F_IN
#define GOUT 32    // F_OUT
#define NCH 4      // feature chunks
#define CHF 32     // feats per chunk
#define SCB 256
#define CH 4096    // edges per bin block
#define WCAP 16384 // scatter LDS window entries
#define CAP 12032  // staging slots per bucket
#define TROW 160   // padded LDS row for cvt kernel
#define UNR 8      // spmm gather unroll

typedef unsigned int uint;
typedef unsigned short ushort;

__device__ __forceinline__ ushort f2bf(float f) {
    uint u = __float_as_uint(f);
    return (ushort)((u + 0x7fffu + ((u >> 16) & 1u)) >> 16);   // RNE
}
__device__ __forceinline__ float bflo(uint u) { return __uint_as_float(u << 16); }
__device__ __forceinline__ float bfhi(uint u) { return __uint_as_float(u & 0xffff0000u); }
__device__ __forceinline__ int tidx(int i) { return i + ((i >> 4) << 2); }

// ---- phase 1: bin edges into per-(block,bucket) staging runs ----
__global__ __launch_bounds__(1024) void bin_kernel(
    const int* __restrict__ ei, const float* __restrict__ ew, int E,
    int* __restrict__ bucketCursor, uint2* __restrict__ staging) {
    __shared__ int hist[256];
    __shared__ int base[256];
    int e0 = blockIdx.x * CH;
    int e1 = min(e0 + CH, E);
    int t = threadIdx.x;
    if (t < 256) hist[t] = 0;
    __syncthreads();
    for (int e = e0 + t; e < e1; e += 1024) {
        int r = ei[e], c = ei[(size_t)E + e];
        if (r != c) atomicAdd(&hist[r >> 8], 1);
    }
    __syncthreads();
    if (t < 256) {
        int h = hist[t];
        if (h > 0) {
            int run = atomicAdd(&bucketCursor[t], h);
            base[t] = t * CAP + run;
        }
        hist[t] = 0;
    }
    __syncthreads();
    for (int e = e0 + t; e < e1; e += 1024) {
        int r = ei[e], c = ei[(size_t)E + e];
        if (r == c) continue;
        float w = ew[e];
        int bk = r >> 8;
        int j = atomicAdd(&hist[bk], 1);
        int idx = base[bk] + j;
        if (idx < (bk + 1) * CAP)   // impossible-overflow guard
            staging[idx] = make_uint2(__float_as_uint(w), ((uint)c << 16) | (uint)(r & 255));
    }
}

// ---- per-row counts from staging (contiguous reads, LDS hist) ----
__global__ __launch_bounds__(256) void bucket_count_kernel(
    const uint2* __restrict__ staging, const int* __restrict__ bucketCursor,
    int* __restrict__ cnt, int n) {
    __shared__ int hist[256];
    int b = blockIdx.x;
    int t = threadIdx.x;
    hist[t] = 0;
    __syncthreads();
    int nrec = bucketCursor[b];
    const uint2* src = staging + (size_t)b * CAP;
    for (int k = t; k < nrec; k += 256)
        atomicAdd(&hist[src[k].y & 255], 1);
    __syncthreads();
    int r = (b << 8) + t;
    if (r < n) cnt[r] = hist[t];
}

// ---- two-level scan (dinv folded into scan1) ----
__global__ void scan1_kernel(const int* __restrict__ cnt, int* __restrict__ partial,
                             int* __restrict__ blockSums, float* __restrict__ dinv, int n) {
    __shared__ int buf[2][SCB];
    int t = threadIdx.x;
    int i = blockIdx.x * SCB + t;
    int v = (i < n) ? cnt[i] : 0;
    if (i < n) dinv[i] = (v > 0) ? rsqrtf((float)v) : 0.0f;
    buf[0][t] = v;
    __syncthreads();
    int src = 0;
    for (int off = 1; off < SCB; off <<= 1) {
        int d = src ^ 1;
        buf[d][t] = buf[src][t] + ((t >= off) ? buf[src][t - off] : 0);
        __syncthreads();
        src = d;
    }
    int incl = buf[src][t];
    if (i < n) partial[i] = incl - v;
    if (t == SCB - 1) blockSums[blockIdx.x] = incl;
}

__global__ void scan2_kernel(const int* __restrict__ blockSums, int* __restrict__ blockOffsets,
                             int nb, int* __restrict__ total_out) {
    __shared__ int buf[2][SCB];
    __shared__ int carry_s;
    if (threadIdx.x == 0) carry_s = 0;
    __syncthreads();
    for (int base = 0; base < nb; base += SCB) {
        int i = base + (int)threadIdx.x;
        int v = (i < nb) ? blockSums[i] : 0;
        buf[0][threadIdx.x] = v;
        __syncthreads();
        int src = 0;
        for (int off = 1; off < SCB; off <<= 1) {
            int d = src ^ 1;
            buf[d][threadIdx.x] = buf[src][threadIdx.x] +
                                  ((threadIdx.x >= (unsigned)off) ? buf[src][threadIdx.x - off] : 0);
            __syncthreads();
            src = d;
        }
        int incl = buf[src][threadIdx.x];
        int c = carry_s;
        if (i < nb) blockOffsets[i] = c + incl - v;
        __syncthreads();
        if (threadIdx.x == SCB - 1) carry_s = c + incl;
        __syncthreads();
    }
    if (threadIdx.x == 0) *total_out = carry_s;
}

__global__ void scan3_kernel(const int* __restrict__ partial, const int* __restrict__ blockOffsets,
                             int* __restrict__ offsets, int n) {
    int i = blockIdx.x * blockDim.x + threadIdx.x;
    if (i < n) offsets[i] = partial[i] + blockOffsets[i / SCB];
}

// ---- phase 2: per-bucket scatter via LDS window -> coalesced csr write ----
__global__ __launch_bounds__(256) void scatter_kernel(
    const uint2* __restrict__ staging, const int* __restrict__ bucketCursor,
    const int* __restrict__ offsets, const float* __restrict__ dinv,
    uint* __restrict__ csr, int n) {
    __shared__ uint win[WCAP];          // 64 KB
    __shared__ int roff[256];
    __shared__ int rcur[256];
    __shared__ float dloc[256];
    int b = blockIdx.x;
    int r0 = b << 8;
    int nrows = min(256, n - r0);
    int t = threadIdx.x;
    if (t < nrows) {
        roff[t] = offsets[r0 + t];
        dloc[t] = dinv[r0 + t];
    }
    rcur[t] = 0;
    __syncthreads();
    int wbeg = roff[0];
    int nrec = bucketCursor[b];
    bool fit = (nrec <= WCAP);
    const uint2* src = staging + (size_t)b * CAP;
    for (int k = t; k < nrec; k += 256) {
        uint2 rec = src[k];
        int col = rec.y >> 16;
        int rl = rec.y & 255;
        float lap = -dloc[rl] * __uint_as_float(rec.x) * dinv[col];
        uint colap = ((uint)col << 16) | (uint)f2bf(lap);
        int pos = roff[rl] + atomicAdd(&rcur[rl], 1);
        if (fit) win[pos - wbeg] = colap;
        else csr[pos] = colap;
    }
    __syncthreads();
    if (fit)
        for (int k = t; k < nrec; k += 256) csr[wbeg + k] = win[k];
}

// ---- fused: x -> CHUNKED bf16 mirror, plus out = bias + x*W0 ----
__global__ __launch_bounds__(256) void cvt_einsum0_kernel(
    const float* __restrict__ x, ushort* __restrict__ xb,
    const float* __restrict__ W0, const float* __restrict__ bias,
    float* __restrict__ out, int n) {
    __shared__ __align__(16) float4 sW4[FEAT * GOUT / 4];
    __shared__ __align__(16) float sT[8 * TROW];
    const float* sW = (const float*)sW4;
    int t = threadIdx.x;
    const float4* wsrc = (const float4*)W0;
    for (int idx = t; idx < FEAT * GOUT / 4; idx += 256) sW4[idx] = wsrc[idx];
    int node = blockIdx.x * 8 + (t >> 5);
    int f0 = 4 * (t & 31);
    float4 v = make_float4(0.f, 0.f, 0.f, 0.f);
    if (node < n) {
        v = *(const float4*)(x + (size_t)node * FEAT + f0);
        ushort4 o;
        o.x = f2bf(v.x); o.y = f2bf(v.y); o.z = f2bf(v.z); o.w = f2bf(v.w);
        int j0 = f0 >> 5;                 // chunk of these 4 feats
        *(ushort4*)(xb + ((size_t)j0 * n + node) * CHF + (f0 & 31)) = o;
    }
    int nl = t >> 5;
    *(float4*)&sT[nl * TROW + tidx(f0)] = v;
    __syncthreads();
    int l32 = t & 31;
    int q = l32 & 7;
    int part = l32 >> 3;
    float4 a4 = make_float4(0.f, 0.f, 0.f, 0.f);
#pragma unroll
    for (int j = 0; j < 8; ++j) {
        float4 t4 = *(const float4*)&sT[nl * TROW + tidx(part * 32 + 4 * j)];
        const float* wv0 = &sW[(part * 32 + 4 * j) * GOUT + 4 * q];
        float4 w0 = *(const float4*)(wv0);
        float4 w1 = *(const float4*)(wv0 + GOUT);
        float4 w2 = *(const float4*)(wv0 + 2 * GOUT);
        float4 w3 = *(const float4*)(wv0 + 3 * GOUT);
        a4.x += t4.x * w0.x + t4.y * w1.x + t4.z * w2.x + t4.w * w3.x;
        a4.y += t4.x * w0.y + t4.y * w1.y + t4.z * w2.y + t4.w * w3.y;
        a4.z += t4.x * w0.z + t4.y * w1.z + t4.z * w2.z + t4.w * w3.z;
        a4.w += t4.x * w0.w + t4.y * w1.w + t4.z * w2.w + t4.w * w3.w;
    }
    a4.x += __shfl_down(a4.x, 8);  a4.y += __shfl_down(a4.y, 8);
    a4.z += __shfl_down(a4.z, 8);  a4.w += __shfl_down(a4.w, 8);
    a4.x += __shfl_down(a4.x, 16); a4.y += __shfl_down(a4.y, 16);
    a4.z += __shfl_down(a4.z, 16); a4.w += __shfl_down(a4.w, 16);
    if (part == 0 && node < n) {
        const float4 b4 = *(const float4*)(bias + 4 * q);
        float4 r;
        r.x = a4.x + b4.x; r.y = a4.y + b4.y; r.z = a4.z + b4.z; r.w = a4.w + b4.w;
        *(float4*)(out + (size_t)node * GOUT + 4 * q) = r;
    }
}

// ---- chunked SpMM pass + partial einsum, LOCAL degree-ranked octets ----
// grid = NCH * nbj (j-major). Block owns 64 contiguous nodes; waves get
// rank-octets of the block's degree order. Lane = uint2 (4 feats).
__global__ __launch_bounds__(512) void spmm_chunk_kernel(
    const ushort* __restrict__ inb, const ushort* __restrict__ sub,
    ushort* __restrict__ outb, const int* __restrict__ offsets,
    const uint* __restrict__ csr, const float* __restrict__ Wk,
    float* __restrict__ out, int n, int has_sub, int write_out, int nbj) {
    __shared__ __align__(16) float sW[CHF * GOUT];   // 4 KB: W rows of this chunk
    __shared__ float sT2[8][8][CHF + 1];             // 8.25 KB, +1 pad (banks)
    __shared__ int sdeg[64];
    __shared__ int sbeg[64];
    __shared__ unsigned char slmap[64];
    int j = blockIdx.x / nbj;
    int b = blockIdx.x % nbj;
    int t = threadIdx.x;
    const float4* wsrc = (const float4*)(Wk + j * CHF * GOUT);
    for (int i2 = t; i2 < CHF * GOUT / 4; i2 += 512) ((float4*)sW)[i2] = wsrc[i2];
    int nb0 = b * 64;
    if (t < 64) {
        int nd = nb0 + t;
        int bg = 0, dg = -1;
        if (nd < n) { bg = offsets[nd]; dg = offsets[nd + 1] - bg; }
        sdeg[t] = dg;
        sbeg[t] = bg;
    }
    __syncthreads();
    if (t < 64) {
        int d = sdeg[t];
        int r = 0;
        for (int k = 0; k < 64; ++k) {
            int dk = sdeg[k];
            r += (dk < d) || (dk == d && k < t);
        }
        slmap[r] = (unsigned char)t;
    }
    __syncthreads();
    int w = t >> 6, lane = t & 63, s = lane >> 3, u = lane & 7;
    int local = slmap[w * 8 + s];
    int node = nb0 + local;
    int deg = sdeg[local];
    int beg = sbeg[local];
    bool alive = deg >= 0;
    if (!alive) deg = 0;
    int m = deg;
    m = max(m, __shfl_xor(m, 8));
    m = max(m, __shfl_xor(m, 16));
    m = max(m, __shfl_xor(m, 32));
    const uint2* inb_u2 = (const uint2*)inb;
    size_t jb2 = (size_t)j * n * 8;                  // chunk base, uint2 units
    size_t obase = jb2 + (size_t)node * 8 + u;
    uint2 sv = make_uint2(0u, 0u);
    if (has_sub && alive) sv = ((const uint2*)sub)[obase];   // early, independent
    float a0 = 0.f, a1 = 0.f, a2 = 0.f, a3 = 0.f;
    for (int it = 0; it < m; it += UNR) {
        uint q[UNR];
        uint2 uu[UNR];
#pragma unroll
        for (int k = 0; k < UNR; ++k) {
            int idx = it + k;
            q[k] = (idx < deg) ? csr[beg + idx] : 0u;
        }
#pragma unroll
        for (int k = 0; k < UNR; ++k)
            uu[k] = inb_u2[jb2 + (size_t)(q[k] >> 16) * 8 + u];
#pragma unroll
        for (int k = 0; k < UNR; ++k) {
            float l = bflo(q[k]);
            a0 += l * bflo(uu[k].x);
            a1 += l * bfhi(uu[k].x);
            a2 += l * bflo(uu[k].y);
            a3 += l * bfhi(uu[k].y);
        }
    }
    if (has_sub) {
        a0 = 2.f * a0 - bflo(sv.x);
        a1 = 2.f * a1 - bfhi(sv.x);
        a2 = 2.f * a2 - bflo(sv.y);
        a3 = 2.f * a3 - bfhi(sv.y);
    }
    if (alive && write_out) {
        uint2 o;
        o.x = (uint)f2bf(a0) | ((uint)f2bf(a1) << 16);
        o.y = (uint)f2bf(a2) | ((uint)f2bf(a3) << 16);
        ((uint2*)outb)[obase] = o;
    }
    sT2[w][s][4 * u + 0] = a0;
    sT2[w][s][4 * u + 1] = a1;
    sT2[w][s][4 * u + 2] = a2;
    sT2[w][s][4 * u + 3] = a3;
    __syncthreads();                      // covers sW staging; sT2 is wave-local
    // partial einsum: lane (s,u) -> out[node_s, u + 8k], k=0..3
    float e0 = 0.f, e1 = 0.f, e2 = 0.f, e3 = 0.f;
#pragma unroll
    for (int i = 0; i < CHF; ++i) {
        float tv = sT2[w][s][i];          // broadcast across u
        e0 += tv * sW[i * GOUT + u];
        e1 += tv * sW[i * GOUT + u + 8];
        e2 += tv * sW[i * GOUT + u + 16];
        e3 += tv * sW[i * GOUT + u + 24];
    }
    if (alive) {
        float* po = out + (size_t)node * GOUT;
        atomicAdd(po + u, e0);
        atomicAdd(po + u + 8, e1);
        atomicAdd(po + u + 16, e2);
        atomicAdd(po + u + 24, e3);
    }
}

extern "C" void kernel_launch(void* const* d_in, const int* in_sizes, int n_in,
                              void* d_out, int out_size, void* d_ws, size_t ws_size,
                              hipStream_t stream) {
    const float* x = (const float*)d_in[0];
    const int* ei = (const int*)d_in[1];     // int32 per harness contract
    const float* ew = (const float*)d_in[2];
    const float* W = (const float*)d_in[3];
    const float* bias = (const float*)d_in[4];
    float* out = (float*)d_out;

    const int N = in_sizes[0] / FEAT;   // 50000
    const int E = in_sizes[1] / 2;      // 1600000
    const int NB = (N + SCB - 1) / SCB;
    const int NBUK = (N + 255) >> 8;    // 196
    // spmm node-blocks (64 nodes/block), padded to x8 for stable XCD mapping
    const int NBJ = (((N + 63) / 64 + 7) / 8) * 8;   // 784

    char* p = (char*)d_ws;
    auto alloc = [&](size_t bytes) {
        char* q = p;
        p += (bytes + 255) & ~(size_t)255;
        return q;
    };
    int* cnt = (int*)alloc((size_t)N * 4);
    int* offsets = (int*)alloc(((size_t)N + 1) * 4);
    float* dinv = (float*)alloc((size_t)N * 4);
    int* partial = (int*)alloc((size_t)N * 4);
    int* blockSums = (int*)alloc((size_t)NB * 4);
    int* blockOffsets = (int*)alloc((size_t)NB * 4);
    int* bucketCursor = (int*)alloc((size_t)NBUK * 4);
    uint* csr = (uint*)alloc(((size_t)E + 64) * 4);  // +pad: predicated over-reads
    ushort* xb = (ushort*)alloc((size_t)N * FEAT * 2);
    ushort* Ab = (ushort*)alloc((size_t)N * FEAT * 2);
    ushort* Bb = (ushort*)alloc((size_t)N * FEAT * 2);
    uint2* staging = (uint2*)Ab;   // aliases Ab+Bb (dead before first spmm)
    (void)ws_size;

    hipMemsetAsync(bucketCursor, 0, (size_t)NBUK * 4, stream);

    bin_kernel<<<(E + CH - 1) / CH, 1024, 0, stream>>>(ei, ew, E, bucketCursor, staging);
    bucket_count_kernel<<<NBUK, 256, 0, stream>>>(staging, bucketCursor, cnt, N);
    scan1_kernel<<<NB, SCB, 0, stream>>>(cnt, partial, blockSums, dinv, N);
    scan2_kernel<<<1, SCB, 0, stream>>>(blockSums, blockOffsets, NB, offsets + N);
    scan3_kernel<<<NB, SCB, 0, stream>>>(partial, blockOffsets, offsets, N);
    scatter_kernel<<<NBUK, 256, 0, stream>>>(staging, bucketCursor, offsets, dinv, csr, N);

    // out = bias + x*W0 ; xb = chunked bf16(x)
    cvt_einsum0_kernel<<<(N + 7) / 8, 256, 0, stream>>>(x, xb, W, bias, out, N);

    dim3 sg(NCH * NBJ);
    // Tx1 = S(x);            out += Tx1*W1
    spmm_chunk_kernel<<<sg, 512, 0, stream>>>(xb, nullptr, Ab, offsets, csr,
                                              W + 1 * FEAT * GOUT, out, N, 0, 1, NBJ);
    // Tx2 = 2*S(Tx1) - x;    out += Tx2*W2
    spmm_chunk_kernel<<<sg, 512, 0, stream>>>(Ab, xb, Bb, offsets, csr,
                                              W + 2 * FEAT * GOUT, out, N, 1, 1, NBJ);
    // Tx3 = 2*S(Tx2) - Tx1;  out += Tx3*W3   (Tx3 mirror never read: no store)
    spmm_chunk_kernel<<<sg, 512, 0, stream>>>(Bb, Ab, nullptr, offsets, csr,
                                              W + 3 * FEAT * GOUT, out, N, 1, 0, NBJ);
}

// Round 13
// 356.569 us; speedup vs baseline: 1.3205x; 1.0462x over previous
//
#include <hip/hip_runtime.h>

// ChebTimeConv: N=50000, E=1.6M, H=4, F_IN=F_OUT=32, K=4, Q=1.
// CSR build: binned counting sort (bin -> bucket_count -> scan -> scatter).
// SpMM: feature-chunked passes ([chunk][node][32f] bf16 mirrors, 3.2 MB
// per-pass working set < 4 MiB/XCD L2), 8 lanes/edge x uint2, unroll 8.
// This round (vs R12): rank-sort REVERTED (barrier made it cosmetic);
// post-loop __syncthreads removed (sW barrier moved before the loop; sT2 is
// wave-local); csr loads software-pipelined one batch ahead to hide the
// csr->gather serial latency. Last spmm skips the dead outb store.
// CSR entry: (col<<16)|bf16(lap). edge_index int32.

#define FEAT 128   // H * F_IN
#define GOUT 32    // F_OUT
#define NCH 4      // feature chunks
#define CHF 32     // feats per chunk
#define SCB 256
#define CH 4096    // edges per bin block
#define WCAP 16384 // scatter LDS window entries
#define CAP 12032  // staging slots per bucket
#define TROW 160   // padded LDS row for cvt kernel
#define UNR 8      // spmm gather unroll

typedef unsigned int uint;
typedef unsigned short ushort;

__device__ __forceinline__ ushort f2bf(float f) {
    uint u = __float_as_uint(f);
    return (ushort)((u + 0x7fffu + ((u >> 16) & 1u)) >> 16);   // RNE
}
__device__ __forceinline__ float bflo(uint u) { return __uint_as_float(u << 16); }
__device__ __forceinline__ float bfhi(uint u) { return __uint_as_float(u & 0xffff0000u); }
__device__ __forceinline__ int tidx(int i) { return i + ((i >> 4) << 2); }

// ---- phase 1: bin edges into per-(block,bucket) staging runs ----
__global__ __launch_bounds__(1024) void bin_kernel(
    const int* __restrict__ ei, const float* __restrict__ ew, int E,
    int* __restrict__ bucketCursor, uint2* __restrict__ staging) {
    __shared__ int hist[256];
    __shared__ int base[256];
    int e0 = blockIdx.x * CH;
    int e1 = min(e0 + CH, E);
    int t = threadIdx.x;
    if (t < 256) hist[t] = 0;
    __syncthreads();
    for (int e = e0 + t; e < e1; e += 1024) {
        int r = ei[e], c = ei[(size_t)E + e];
        if (r != c) atomicAdd(&hist[r >> 8], 1);
    }
    __syncthreads();
    if (t < 256) {
        int h = hist[t];
        if (h > 0) {
            int run = atomicAdd(&bucketCursor[t], h);
            base[t] = t * CAP + run;
        }
        hist[t] = 0;
    }
    __syncthreads();
    for (int e = e0 + t; e < e1; e += 1024) {
        int r = ei[e], c = ei[(size_t)E + e];
        if (r == c) continue;
        float w = ew[e];
        int bk = r >> 8;
        int j = atomicAdd(&hist[bk], 1);
        int idx = base[bk] + j;
        if (idx < (bk + 1) * CAP)   // impossible-overflow guard
            staging[idx] = make_uint2(__float_as_uint(w), ((uint)c << 16) | (uint)(r & 255));
    }
}

// ---- per-row counts from staging (contiguous reads, LDS hist) ----
__global__ __launch_bounds__(256) void bucket_count_kernel(
    const uint2* __restrict__ staging, const int* __restrict__ bucketCursor,
    int* __restrict__ cnt, int n) {
    __shared__ int hist[256];
    int b = blockIdx.x;
    int t = threadIdx.x;
    hist[t] = 0;
    __syncthreads();
    int nrec = bucketCursor[b];
    const uint2* src = staging + (size_t)b * CAP;
    for (int k = t; k < nrec; k += 256)
        atomicAdd(&hist[src[k].y & 255], 1);
    __syncthreads();
    int r = (b << 8) + t;
    if (r < n) cnt[r] = hist[t];
}

// ---- two-level scan (dinv folded into scan1) ----
__global__ void scan1_kernel(const int* __restrict__ cnt, int* __restrict__ partial,
                             int* __restrict__ blockSums, float* __restrict__ dinv, int n) {
    __shared__ int buf[2][SCB];
    int t = threadIdx.x;
    int i = blockIdx.x * SCB + t;
    int v = (i < n) ? cnt[i] : 0;
    if (i < n) dinv[i] = (v > 0) ? rsqrtf((float)v) : 0.0f;
    buf[0][t] = v;
    __syncthreads();
    int src = 0;
    for (int off = 1; off < SCB; off <<= 1) {
        int d = src ^ 1;
        buf[d][t] = buf[src][t] + ((t >= off) ? buf[src][t - off] : 0);
        __syncthreads();
        src = d;
    }
    int incl = buf[src][t];
    if (i < n) partial[i] = incl - v;
    if (t == SCB - 1) blockSums[blockIdx.x] = incl;
}

__global__ void scan2_kernel(const int* __restrict__ blockSums, int* __restrict__ blockOffsets,
                             int nb, int* __restrict__ total_out) {
    __shared__ int buf[2][SCB];
    __shared__ int carry_s;
    if (threadIdx.x == 0) carry_s = 0;
    __syncthreads();
    for (int base = 0; base < nb; base += SCB) {
        int i = base + (int)threadIdx.x;
        int v = (i < nb) ? blockSums[i] : 0;
        buf[0][threadIdx.x] = v;
        __syncthreads();
        int src = 0;
        for (int off = 1; off < SCB; off <<= 1) {
            int d = src ^ 1;
            buf[d][threadIdx.x] = buf[src][threadIdx.x] +
                                  ((threadIdx.x >= (unsigned)off) ? buf[src][threadIdx.x - off] : 0);
            __syncthreads();
            src = d;
        }
        int incl = buf[src][threadIdx.x];
        int c = carry_s;
        if (i < nb) blockOffsets[i] = c + incl - v;
        __syncthreads();
        if (threadIdx.x == SCB - 1) carry_s = c + incl;
        __syncthreads();
    }
    if (threadIdx.x == 0) *total_out = carry_s;
}

__global__ void scan3_kernel(const int* __restrict__ partial, const int* __restrict__ blockOffsets,
                             int* __restrict__ offsets, int n) {
    int i = blockIdx.x * blockDim.x + threadIdx.x;
    if (i < n) offsets[i] = partial[i] + blockOffsets[i / SCB];
}

// ---- phase 2: per-bucket scatter via LDS window -> coalesced csr write ----
__global__ __launch_bounds__(256) void scatter_kernel(
    const uint2* __restrict__ staging, const int* __restrict__ bucketCursor,
    const int* __restrict__ offsets, const float* __restrict__ dinv,
    uint* __restrict__ csr, int n) {
    __shared__ uint win[WCAP];          // 64 KB
    __shared__ int roff[256];
    __shared__ int rcur[256];
    __shared__ float dloc[256];
    int b = blockIdx.x;
    int r0 = b << 8;
    int nrows = min(256, n - r0);
    int t = threadIdx.x;
    if (t < nrows) {
        roff[t] = offsets[r0 + t];
        dloc[t] = dinv[r0 + t];
    }
    rcur[t] = 0;
    __syncthreads();
    int wbeg = roff[0];
    int nrec = bucketCursor[b];
    bool fit = (nrec <= WCAP);
    const uint2* src = staging + (size_t)b * CAP;
    for (int k = t; k < nrec; k += 256) {
        uint2 rec = src[k];
        int col = rec.y >> 16;
        int rl = rec.y & 255;
        float lap = -dloc[rl] * __uint_as_float(rec.x) * dinv[col];
        uint colap = ((uint)col << 16) | (uint)f2bf(lap);
        int pos = roff[rl] + atomicAdd(&rcur[rl], 1);
        if (fit) win[pos - wbeg] = colap;
        else csr[pos] = colap;
    }
    __syncthreads();
    if (fit)
        for (int k = t; k < nrec; k += 256) csr[wbeg + k] = win[k];
}

// ---- fused: x -> CHUNKED bf16 mirror, plus out = bias + x*W0 ----
__global__ __launch_bounds__(256) void cvt_einsum0_kernel(
    const float* __restrict__ x, ushort* __restrict__ xb,
    const float* __restrict__ W0, const float* __restrict__ bias,
    float* __restrict__ out, int n) {
    __shared__ __align__(16) float4 sW4[FEAT * GOUT / 4];
    __shared__ __align__(16) float sT[8 * TROW];
    const float* sW = (const float*)sW4;
    int t = threadIdx.x;
    const float4* wsrc = (const float4*)W0;
    for (int idx = t; idx < FEAT * GOUT / 4; idx += 256) sW4[idx] = wsrc[idx];
    int node = blockIdx.x * 8 + (t >> 5);
    int f0 = 4 * (t & 31);
    float4 v = make_float4(0.f, 0.f, 0.f, 0.f);
    if (node < n) {
        v = *(const float4*)(x + (size_t)node * FEAT + f0);
        ushort4 o;
        o.x = f2bf(v.x); o.y = f2bf(v.y); o.z = f2bf(v.z); o.w = f2bf(v.w);
        int j0 = f0 >> 5;                 // chunk of these 4 feats
        *(ushort4*)(xb + ((size_t)j0 * n + node) * CHF + (f0 & 31)) = o;
    }
    int nl = t >> 5;
    *(float4*)&sT[nl * TROW + tidx(f0)] = v;
    __syncthreads();
    int l32 = t & 31;
    int q = l32 & 7;
    int part = l32 >> 3;
    float4 a4 = make_float4(0.f, 0.f, 0.f, 0.f);
#pragma unroll
    for (int j = 0; j < 8; ++j) {
        float4 t4 = *(const float4*)&sT[nl * TROW + tidx(part * 32 + 4 * j)];
        const float* wv0 = &sW[(part * 32 + 4 * j) * GOUT + 4 * q];
        float4 w0 = *(const float4*)(wv0);
        float4 w1 = *(const float4*)(wv0 + GOUT);
        float4 w2 = *(const float4*)(wv0 + 2 * GOUT);
        float4 w3 = *(const float4*)(wv0 + 3 * GOUT);
        a4.x += t4.x * w0.x + t4.y * w1.x + t4.z * w2.x + t4.w * w3.x;
        a4.y += t4.x * w0.y + t4.y * w1.y + t4.z * w2.y + t4.w * w3.y;
        a4.z += t4.x * w0.z + t4.y * w1.z + t4.z * w2.z + t4.w * w3.z;
        a4.w += t4.x * w0.w + t4.y * w1.w + t4.z * w2.w + t4.w * w3.w;
    }
    a4.x += __shfl_down(a4.x, 8);  a4.y += __shfl_down(a4.y, 8);
    a4.z += __shfl_down(a4.z, 8);  a4.w += __shfl_down(a4.w, 8);
    a4.x += __shfl_down(a4.x, 16); a4.y += __shfl_down(a4.y, 16);
    a4.z += __shfl_down(a4.z, 16); a4.w += __shfl_down(a4.w, 16);
    if (part == 0 && node < n) {
        const float4 b4 = *(const float4*)(bias + 4 * q);
        float4 r;
        r.x = a4.x + b4.x; r.y = a4.y + b4.y; r.z = a4.z + b4.z; r.w = a4.w + b4.w;
        *(float4*)(out + (size_t)node * GOUT + 4 * q) = r;
    }
}

// ---- chunked SpMM pass + partial einsum ----
// grid = NCH * nbj (j-major). Wave = 8 contiguous nodes x 8 lanes (uint2).
// csr loads pipelined one batch ahead; no post-loop block barrier.
__global__ __launch_bounds__(512) void spmm_chunk_kernel(
    const ushort* __restrict__ inb, const ushort* __restrict__ sub,
    ushort* __restrict__ outb, const int* __restrict__ offsets,
    const uint* __restrict__ csr, const float* __restrict__ Wk,
    float* __restrict__ out, int n, int has_sub, int write_out, int nbj) {
    __shared__ __align__(16) float sW[CHF * GOUT];   // 4 KB: W rows of this chunk
    __shared__ float sT2[8][8][CHF + 1];             // 8.25 KB, +1 pad (banks)
    int j = blockIdx.x / nbj;
    int b = blockIdx.x % nbj;
    int t = threadIdx.x;
    const float4* wsrc = (const float4*)(Wk + j * CHF * GOUT);
    for (int i2 = t; i2 < CHF * GOUT / 4; i2 += 512) ((float4*)sW)[i2] = wsrc[i2];
    __syncthreads();                    // sW staged; only barrier in kernel
    int w = t >> 6, lane = t & 63, s = lane >> 3, u = lane & 7;
    int node = b * 64 + w * 8 + s;
    bool alive = node < n;
    int beg = 0, deg = 0;
    if (alive) { beg = offsets[node]; deg = offsets[node + 1] - beg; }
    int m = deg;
    m = max(m, __shfl_xor(m, 8));
    m = max(m, __shfl_xor(m, 16));
    m = max(m, __shfl_xor(m, 32));
    const uint2* inb_u2 = (const uint2*)inb;
    size_t jb2 = (size_t)j * n * 8;                  // chunk base, uint2 units
    size_t obase = jb2 + (size_t)node * 8 + u;
    uint2 sv = make_uint2(0u, 0u);
    if (has_sub && alive) sv = ((const uint2*)sub)[obase];   // early, independent
    float a0 = 0.f, a1 = 0.f, a2 = 0.f, a3 = 0.f;
    uint q[UNR];
#pragma unroll
    for (int k = 0; k < UNR; ++k)
        q[k] = (k < deg) ? csr[beg + k] : 0u;        // prologue csr batch
    for (int it = 0; it < m; it += UNR) {
        uint2 uu[UNR];
#pragma unroll
        for (int k = 0; k < UNR; ++k)                // gathers for current batch
            uu[k] = inb_u2[jb2 + (size_t)(q[k] >> 16) * 8 + u];
        uint qn[UNR];
        int nx = it + UNR;
#pragma unroll
        for (int k = 0; k < UNR; ++k)                // prefetch next csr batch
            qn[k] = (nx + k < deg) ? csr[beg + nx + k] : 0u;
#pragma unroll
        for (int k = 0; k < UNR; ++k) {
            float l = bflo(q[k]);
            a0 += l * bflo(uu[k].x);
            a1 += l * bfhi(uu[k].x);
            a2 += l * bflo(uu[k].y);
            a3 += l * bfhi(uu[k].y);
        }
#pragma unroll
        for (int k = 0; k < UNR; ++k) q[k] = qn[k];
    }
    if (has_sub) {
        a0 = 2.f * a0 - bflo(sv.x);
        a1 = 2.f * a1 - bfhi(sv.x);
        a2 = 2.f * a2 - bflo(sv.y);
        a3 = 2.f * a3 - bfhi(sv.y);
    }
    if (alive && write_out) {
        uint2 o;
        o.x = (uint)f2bf(a0) | ((uint)f2bf(a1) << 16);
        o.y = (uint)f2bf(a2) | ((uint)f2bf(a3) << 16);
        ((uint2*)outb)[obase] = o;
    }
    // wave-local transpose through LDS (no block barrier: sT2[w] is written
    // and read only by wave w; wave64 lockstep + lgkmcnt ordering suffice)
    sT2[w][s][4 * u + 0] = a0;
    sT2[w][s][4 * u + 1] = a1;
    sT2[w][s][4 * u + 2] = a2;
    sT2[w][s][4 * u + 3] = a3;
    __builtin_amdgcn_wave_barrier();
    // partial einsum: lane (s,u) -> out[node_s, u + 8k], k=0..3
    float e0 = 0.f, e1 = 0.f, e2 = 0.f, e3 = 0.f;
#pragma unroll
    for (int i = 0; i < CHF; ++i) {
        float tv = sT2[w][s][i];          // broadcast across u
        e0 += tv * sW[i * GOUT + u];
        e1 += tv * sW[i * GOUT + u + 8];
        e2 += tv * sW[i * GOUT + u + 16];
        e3 += tv * sW[i * GOUT + u + 24];
    }
    if (alive) {
        float* po = out + (size_t)node * GOUT;
        atomicAdd(po + u, e0);
        atomicAdd(po + u + 8, e1);
        atomicAdd(po + u + 16, e2);
        atomicAdd(po + u + 24, e3);
    }
}

extern "C" void kernel_launch(void* const* d_in, const int* in_sizes, int n_in,
                              void* d_out, int out_size, void* d_ws, size_t ws_size,
                              hipStream_t stream) {
    const float* x = (const float*)d_in[0];
    const int* ei = (const int*)d_in[1];     // int32 per harness contract
    const float* ew = (const float*)d_in[2];
    const float* W = (const float*)d_in[3];
    const float* bias = (const float*)d_in[4];
    float* out = (float*)d_out;

    const int N = in_sizes[0] / FEAT;   // 50000
    const int E = in_sizes[1] / 2;      // 1600000
    const int NB = (N + SCB - 1) / SCB;
    const int NBUK = (N + 255) >> 8;    // 196
    // spmm node-blocks (64 nodes/block), padded to x8 for stable XCD mapping
    const int NBJ = (((N + 63) / 64 + 7) / 8) * 8;   // 784

    char* p = (char*)d_ws;
    auto alloc = [&](size_t bytes) {
        char* q = p;
        p += (bytes + 255) & ~(size_t)255;
        return q;
    };
    int* cnt = (int*)alloc((size_t)N * 4);
    int* offsets = (int*)alloc(((size_t)N + 1) * 4);
    float* dinv = (float*)alloc((size_t)N * 4);
    int* partial = (int*)alloc((size_t)N * 4);
    int* blockSums = (int*)alloc((size_t)NB * 4);
    int* blockOffsets = (int*)alloc((size_t)NB * 4);
    int* bucketCursor = (int*)alloc((size_t)NBUK * 4);
    uint* csr = (uint*)alloc(((size_t)E + 64) * 4);  // +pad: predicated over-reads
    ushort* xb = (ushort*)alloc((size_t)N * FEAT * 2);
    ushort* Ab = (ushort*)alloc((size_t)N * FEAT * 2);
    ushort* Bb = (ushort*)alloc((size_t)N * FEAT * 2);
    uint2* staging = (uint2*)Ab;   // aliases Ab+Bb (dead before first spmm)
    (void)ws_size;

    hipMemsetAsync(bucketCursor, 0, (size_t)NBUK * 4, stream);

    bin_kernel<<<(E + CH - 1) / CH, 1024, 0, stream>>>(ei, ew, E, bucketCursor, staging);
    bucket_count_kernel<<<NBUK, 256, 0, stream>>>(staging, bucketCursor, cnt, N);
    scan1_kernel<<<NB, SCB, 0, stream>>>(cnt, partial, blockSums, dinv, N);
    scan2_kernel<<<1, SCB, 0, stream>>>(blockSums, blockOffsets, NB, offsets + N);
    scan3_kernel<<<NB, SCB, 0, stream>>>(partial, blockOffsets, offsets, N);
    scatter_kernel<<<NBUK, 256, 0, stream>>>(staging, bucketCursor, offsets, dinv, csr, N);

    // out = bias + x*W0 ; xb = chunked bf16(x)
    cvt_einsum0_kernel<<<(N + 7) / 8, 256, 0, stream>>>(x, xb, W, bias, out, N);

    dim3 sg(NCH * NBJ);
    // Tx1 = S(x);            out += Tx1*W1
    spmm_chunk_kernel<<<sg, 512, 0, stream>>>(xb, nullptr, Ab, offsets, csr,
                                              W + 1 * FEAT * GOUT, out, N, 0, 1, NBJ);
    // Tx2 = 2*S(Tx1) - x;    out += Tx2*W2
    spmm_chunk_kernel<<<sg, 512, 0, stream>>>(Ab, xb, Bb, offsets, csr,
                                              W + 2 * FEAT * GOUT, out, N, 1, 1, NBJ);
    // Tx3 = 2*S(Tx2) - Tx1;  out += Tx3*W3   (Tx3 mirror never read: no store)
    spmm_chunk_kernel<<<sg, 512, 0, stream>>>(Bb, Ab, nullptr, offsets, csr,
                                              W + 3 * FEAT * GOUT, out, N, 1, 0, NBJ);
}